// Round 3
// baseline (61.002 us; speedup 1.0000x reference)
//
#include <hip/hip_runtime.h>
#include <hip/hip_bf16.h>
#include <stdint.h>

// Problem constants
#define D       256
#define KCB     1024
#define HW      1024        // 32*32
#define NROWS   32768       // 32*32*32
#define TOTAL   8388608     // 32*256*32*32
#define BM      64
#define BN      64

// ws layout (bytes)
#define WS_EMBBF 0          // 1024*256*2 = 524288, pre-swizzled bf16, 16 tiles x 32KB
#define WS_EMBSQ 524288     // 1024*4
#define WS_IDX   528384     // 32768*4
#define WS_PART  659456     // 2048*4

typedef __bf16 bf16x8 __attribute__((ext_vector_type(8)));
typedef float  f32x4  __attribute__((ext_vector_type(4)));
typedef unsigned int u32x4 __attribute__((ext_vector_type(4)));
typedef unsigned int u32x2 __attribute__((ext_vector_type(2)));

union Pack8 { __bf16 h[8]; u32x4 u; };
union Pack4 { __bf16 h[4]; u32x2 u; };

__device__ __forceinline__ void gload_lds16(const void* g, void* l) {
  __builtin_amdgcn_global_load_lds(
      (__attribute__((address_space(1))) void*)(uintptr_t)g,
      (__attribute__((address_space(3))) void*)l, 16, 0, 0);
}

// ---------------- K1: embsq + bf16 emb, pre-swizzled for linear LDS fill ----
// One wave per codebook row. Swizzle: data byte-col c stored at c ^ ((row&7)<<4).
__global__ __launch_bounds__(256) void k_prep(const float* __restrict__ emb,
                                              unsigned char* __restrict__ ws) {
  const int t = threadIdx.x;
  const int wave = (blockIdx.x * 256 + t) >> 6;  // 0..1023 = emb row
  const int lane = t & 63;
  const float4 v = *reinterpret_cast<const float4*>(emb + wave * D + lane * 4);
  float ss = v.x * v.x + v.y * v.y + v.z * v.z + v.w * v.w;
  #pragma unroll
  for (int m = 1; m < 64; m <<= 1) ss += __shfl_xor(ss, m, 64);
  if (lane == 0) *reinterpret_cast<float*>(ws + WS_EMBSQ + wave * 4) = ss;

  Pack4 p;
  p.h[0] = (__bf16)v.x; p.h[1] = (__bf16)v.y; p.h[2] = (__bf16)v.z; p.h[3] = (__bf16)v.w;
  const int tile = wave >> 6, rl = wave & 63;
  const unsigned u = (unsigned)(lane * 8) ^ (unsigned)((rl & 7) << 4);
  *reinterpret_cast<u32x2*>(ws + WS_EMBBF + tile * 32768 + rl * 512 + u) = p.u;
}

// ---------------- K2: fused distances + argmin ------------------------------
// 512 WGs x 256 threads. WG = 64 z-rows vs all 1024 codes, bf16 MFMA 16x16x32.
__global__ __launch_bounds__(256) void k_dist(const float* __restrict__ z,
                                              const unsigned char* __restrict__ embbf,
                                              const float* __restrict__ embsq,
                                              int* __restrict__ idx_out) {
  __shared__ unsigned char z_lds[BM * 512];   // 32KB swizzled bf16 [row][256 d]
  __shared__ unsigned char e_lds[BN * 512];   // 32KB; doubles as f32 transpose scratch

  const int t    = threadIdx.x;
  const int lane = t & 63;
  const int w    = t >> 6;
  const int row0 = blockIdx.x * BM;
  const int b    = row0 >> 10;
  const int hw0  = row0 & 1023;
  const float* zb = z + (size_t)b * (D * HW) + hw0;

  float* scratch = reinterpret_cast<float*>(e_lds);  // 128 d x 64 hw chunk

  // Stage z tile: global [d][hw] (coalesced) -> scratch -> transpose -> bf16 swizzled LDS
  for (int c = 0; c < 2; ++c) {
    #pragma unroll
    for (int i = 0; i < 32; ++i) {
      const int dl = i * 4 + w;
      scratch[dl * 64 + lane] = zb[(size_t)(c * 128 + dl) * HW + lane];
    }
    __syncthreads();
    #pragma unroll
    for (int j = 0; j < 4; ++j) {
      const int cid = j * 256 + t;
      const int row = cid & 63;
      const int kc  = cid >> 6;       // 0..15 (8 d each)
      Pack8 p;
      #pragma unroll
      for (int q = 0; q < 8; ++q) p.h[q] = (__bf16)scratch[(kc * 8 + q) * 64 + row];
      const unsigned u = (unsigned)(c * 256 + kc * 16) ^ (unsigned)((row & 7) << 4);
      *reinterpret_cast<u32x4*>(&z_lds[row * 512 + u]) = p.u;
    }
    __syncthreads();
  }

  // Hoist A-fragments (z is stationary across all codebook tiles)
  bf16x8 afrag[8];
  {
    const int rl = w * 16 + (lane & 15);
    const unsigned s = (unsigned)((rl & 7) << 4);
    #pragma unroll
    for (int kb = 0; kb < 8; ++kb) {
      const unsigned dbyte = (unsigned)(kb * 64 + (lane >> 4) * 16);
      afrag[kb] = *reinterpret_cast<const bf16x8*>(&z_lds[rl * 512 + (dbyte ^ s)]);
    }
  }

  float minv[4] = {3.4e38f, 3.4e38f, 3.4e38f, 3.4e38f};
  int   mini[4] = {0, 0, 0, 0};
  const int crl = lane & 15;
  const unsigned dphase = (unsigned)((lane >> 4) * 16);

  for (int tile = 0; tile < 16; ++tile) {
    // stage code tile: pre-swizzled ws -> linear LDS via global_load_lds (16B)
    {
      const unsigned char* src = embbf + tile * 32768 + w * 8192 + lane * 16;
      unsigned char* dst = e_lds + w * 8192;   // wave-uniform base
      #pragma unroll
      for (int i = 0; i < 8; ++i) gload_lds16(src + i * 1024, dst + i * 1024);
    }
    __syncthreads();   // drains vmcnt before any wave reads

    f32x4 acc[4];
    #pragma unroll
    for (int n = 0; n < 4; ++n) { acc[n][0] = 0.f; acc[n][1] = 0.f; acc[n][2] = 0.f; acc[n][3] = 0.f; }

    #pragma unroll
    for (int kb = 0; kb < 8; ++kb) {
      const unsigned dbyte = (unsigned)(kb * 64) + dphase;
      #pragma unroll
      for (int n = 0; n < 4; ++n) {
        const int er = n * 16 + crl;
        const bf16x8 bfr = *reinterpret_cast<const bf16x8*>(
            &e_lds[er * 512 + (dbyte ^ (unsigned)((er & 7) << 4))]);
        acc[n] = __builtin_amdgcn_mfma_f32_16x16x32_bf16(afrag[kb], bfr, acc[n], 0, 0, 0);
      }
    }

    // epilogue: dist = |e|^2 - 2*dot ; running min (cols ascend -> first-min kept)
    #pragma unroll
    for (int n = 0; n < 4; ++n) {
      const int colg = tile * 64 + n * 16 + crl;
      const float es = embsq[colg];
      #pragma unroll
      for (int r = 0; r < 4; ++r) {
        const float dist = es - 2.0f * acc[n][r];
        if (dist < minv[r]) { minv[r] = dist; mini[r] = colg; }
      }
    }
    __syncthreads();   // protect e_lds before next tile's staging
  }

  // min-reduce across the 16 lanes of each C/D row-group (ties -> lower index)
  #pragma unroll
  for (int m = 1; m <= 8; m <<= 1) {
    #pragma unroll
    for (int r = 0; r < 4; ++r) {
      const float ov = __shfl_xor(minv[r], m, 64);
      const int   oi = __shfl_xor(mini[r], m, 64);
      if (ov < minv[r] || (ov == minv[r] && oi < mini[r])) { minv[r] = ov; mini[r] = oi; }
    }
  }
  if ((lane & 15) == 0) {
    #pragma unroll
    for (int r = 0; r < 4; ++r)
      idx_out[row0 + w * 16 + (lane >> 4) * 4 + r] = mini[r];
  }
}

// ---------------- K3: gather + straight-through output + loss partials ------
// item = (nblk, dc, lane_n): lanes -> consecutive hw (coalesced z/out); per-lane
// float4 gather on emb (L2-resident).
__global__ __launch_bounds__(256) void k_out(const float* __restrict__ z,
                                             const float* __restrict__ emb,
                                             const int* __restrict__ idx,
                                             float* __restrict__ out,
                                             float* __restrict__ partials) {
  const int t = threadIdx.x;
  const int gid = blockIdx.x * 256 + t;
  float lsum = 0.f;
  #pragma unroll
  for (int it = 0; it < 4; ++it) {
    const int i = gid + it * (2048 * 256);   // 0 .. 2097151 = 32768 n * 64 d-chunks
    const int lane_n = i & 63;
    const int rest = i >> 6;
    const int dc = rest & 63;
    const int nblk = rest >> 6;
    const int n = nblk * 64 + lane_n;
    const int d0 = dc * 4;
    const int k = idx[n];
    const float4 e4 = *reinterpret_cast<const float4*>(emb + k * D + d0);
    const int bq = n >> 10, hw = n & 1023;
    const size_t base = (size_t)bq * (D * HW) + (size_t)d0 * HW + hw;
    const float ev[4] = {e4.x, e4.y, e4.z, e4.w};
    #pragma unroll
    for (int q = 0; q < 4; ++q) {
      const size_t off = base + (size_t)q * HW;
      const float zv = z[off];
      const float qv = ev[q];
      out[off] = zv + (qv - zv);     // straight-through, same fp32 expr as ref
      const float dl = qv - zv;
      lsum += dl * dl;
    }
  }
  #pragma unroll
  for (int m = 1; m < 64; m <<= 1) lsum += __shfl_xor(lsum, m, 64);
  __shared__ float wsum[4];
  if ((t & 63) == 0) wsum[t >> 6] = lsum;
  __syncthreads();
  if (t == 0) partials[blockIdx.x] = wsum[0] + wsum[1] + wsum[2] + wsum[3];
}

// ---------------- K4: final loss reduce -------------------------------------
__global__ __launch_bounds__(256) void k_loss(const float* __restrict__ partials,
                                              float* __restrict__ out_loss) {
  const int t = threadIdx.x;
  float s = 0.f;
  #pragma unroll
  for (int i = 0; i < 8; ++i) s += partials[t + i * 256];
  #pragma unroll
  for (int m = 1; m < 64; m <<= 1) s += __shfl_xor(s, m, 64);
  __shared__ float wsum[4];
  if ((t & 63) == 0) wsum[t >> 6] = s;
  __syncthreads();
  if (t == 0)
    out_loss[0] = 1.25f * (wsum[0] + wsum[1] + wsum[2] + wsum[3]) * (1.0f / 8388608.0f);
}

extern "C" void kernel_launch(void* const* d_in, const int* in_sizes, int n_in,
                              void* d_out, int out_size, void* d_ws, size_t ws_size,
                              hipStream_t stream) {
  (void)in_sizes; (void)n_in; (void)out_size; (void)ws_size;
  const float* z   = (const float*)d_in[0];
  const float* emb = (const float*)d_in[1];
  float* out = (float*)d_out;
  unsigned char* ws = (unsigned char*)d_ws;

  k_prep<<<256, 256, 0, stream>>>(emb, ws);
  k_dist<<<512, 256, 0, stream>>>(z, ws + WS_EMBBF,
                                  (const float*)(ws + WS_EMBSQ),
                                  (int*)(ws + WS_IDX));
  k_out<<<2048, 256, 0, stream>>>(z, emb, (const int*)(ws + WS_IDX), out,
                                  (float*)(ws + WS_PART));
  k_loss<<<1, 256, 0, stream>>>((const float*)(ws + WS_PART), out + TOTAL);
}

// Round 4
// 58.753 us; speedup vs baseline: 1.0383x; 1.0383x over previous
//
#include <hip/hip_runtime.h>
#include <hip/hip_bf16.h>
#include <stdint.h>

// Problem constants
#define D       256
#define KCB     1024
#define HW      1024        // 32*32
#define NROWS   32768       // 32*32*32
#define TOTAL   8388608     // 32*256*32*32
#define BM      128         // z-rows per WG in k_dist

// ws layout (bytes)
#define WS_EMBBF 0          // 1024*256*2 = 524288, pre-swizzled bf16, 16 tiles x 32KB
#define WS_CINIT 524288     // 1024*4  : 1 - 0.5*|e|^2 per code
#define WS_IDX   528384     // 32768*4
#define WS_PART  659456     // 2048*4

typedef __bf16 bf16x8 __attribute__((ext_vector_type(8)));
typedef float  f32x4  __attribute__((ext_vector_type(4)));
typedef unsigned int u32x4 __attribute__((ext_vector_type(4)));
typedef unsigned int u32x2 __attribute__((ext_vector_type(2)));

union Pack8 { __bf16 h[8]; u32x4 u; };
union Pack4 { __bf16 h[4]; u32x2 u; };
union FU    { float f; unsigned u; };

__device__ __forceinline__ void gload_lds16(const void* g, void* l) {
  __builtin_amdgcn_global_load_lds(
      (__attribute__((address_space(1))) void*)(uintptr_t)g,
      (__attribute__((address_space(3))) void*)l, 16, 0, 0);
}

// ---------------- K1: c_init (1 - 0.5|e|^2) + bf16 emb, pre-swizzled --------
// One wave per codebook row. Data byte-col c stored at c ^ ((row&7)<<4).
__global__ __launch_bounds__(256) void k_prep(const float* __restrict__ emb,
                                              unsigned char* __restrict__ ws) {
  const int t = threadIdx.x;
  const int wave = (blockIdx.x * 256 + t) >> 6;  // 0..1023 = emb row
  const int lane = t & 63;
  const float4 v = *reinterpret_cast<const float4*>(emb + wave * D + lane * 4);
  float ss = v.x * v.x + v.y * v.y + v.z * v.z + v.w * v.w;
  #pragma unroll
  for (int m = 1; m < 64; m <<= 1) ss += __shfl_xor(ss, m, 64);
  if (lane == 0)
    *reinterpret_cast<float*>(ws + WS_CINIT + wave * 4) = 1.0f - 0.5f * ss;

  Pack4 p;
  p.h[0] = (__bf16)v.x; p.h[1] = (__bf16)v.y; p.h[2] = (__bf16)v.z; p.h[3] = (__bf16)v.w;
  const int tile = wave >> 6, rl = wave & 63;
  const unsigned u = (unsigned)(lane * 8) ^ (unsigned)((rl & 7) << 4);
  *reinterpret_cast<u32x2*>(ws + WS_EMBBF + tile * 32768 + rl * 512 + u) = p.u;
}

// ---------------- K2: fused distances + argmin ------------------------------
// 256 WGs x 512 threads (8 waves, 2/SIMD). WG = 128 z-rows vs all 1024 codes.
// Wave tile 64M x 16N: A(z) stationary in regs (afrag[4][8]), B double-buffered
// in LDS, 1 barrier per tile. argmin via bit-packed key: acc = 1 + z.e - .5|e|^2
// (positive -> bits monotone); key = (bits & ~1023) | (1023-col); running max.
__global__ __launch_bounds__(512, 2) void k_dist(const float* __restrict__ z,
                                                 const unsigned char* __restrict__ embbf,
                                                 const float* __restrict__ c_init,
                                                 int* __restrict__ idx_out) {
  __shared__ unsigned char z_lds[BM * 512];      // 64KB swizzled bf16 [row][256 d]
  __shared__ unsigned char e_lds[2][32768];      // 64KB dbuf; [1] doubles as scratch/kbuf

  const int t    = threadIdx.x;
  const int lane = t & 63;
  const int w    = t >> 6;        // 0..7
  const int wm   = w >> 2;        // 0..1 : 64-row block
  const int wn   = w & 3;         // 0..3 : 16-col block within each 64-col tile
  const int crl  = lane & 15;
  const int g    = lane >> 4;     // 0..3
  const int row0 = blockIdx.x * BM;
  const int b    = row0 >> 10;
  const int hw0  = row0 & 1023;
  const float* zb = z + (size_t)b * (D * HW) + hw0;

  // Prefetch code tile 0 into e_lds[0] (async, overlaps z staging)
  #pragma unroll
  for (int i = 0; i < 4; ++i)
    gload_lds16(embbf + i * 8192 + w * 1024 + lane * 16,
                &e_lds[0][i * 8192 + w * 1024]);

  // ---- Stage z tile: global [d][hw] -> f32 scratch -> transposed bf16 swz LDS
  float* scratch = reinterpret_cast<float*>(e_lds[1]);  // 32 d x 128 hw chunk
  for (int c = 0; c < 8; ++c) {
    const int hw_l = t & 127;
    const int dg   = t >> 7;                    // 0..3
    #pragma unroll
    for (int i = 0; i < 8; ++i) {
      const int dl = i * 4 + dg;
      scratch[dl * 128 + hw_l] = zb[(size_t)(c * 32 + dl) * HW + hw_l];
    }
    __syncthreads();
    {
      const int row = t & 127;
      const int kc  = t >> 7;                   // 0..3 (8 d each)
      Pack8 p;
      #pragma unroll
      for (int q = 0; q < 8; ++q) p.h[q] = (__bf16)scratch[(kc * 8 + q) * 128 + row];
      const unsigned u = (unsigned)(c * 64 + kc * 16) ^ (unsigned)((row & 7) << 4);
      *reinterpret_cast<u32x4*>(&z_lds[row * 512 + u]) = p.u;
    }
    __syncthreads();
  }

  // ---- Hoist A-fragments: 64 rows x full K per wave (128 VGPR, stationary)
  bf16x8 afrag[4][8];
  #pragma unroll
  for (int m = 0; m < 4; ++m) {
    const int rl = wm * 64 + m * 16 + crl;
    const unsigned s = (unsigned)((rl & 7) << 4);
    #pragma unroll
    for (int kb = 0; kb < 8; ++kb) {
      const unsigned db = (unsigned)(kb * 64 + g * 16) ^ s;
      afrag[m][kb] = *reinterpret_cast<const bf16x8*>(&z_lds[rl * 512 + db]);
    }
  }
  __syncthreads();   // tile 0 staged & visible; scratch dead

  unsigned kmax[4][4];
  #pragma unroll
  for (int m = 0; m < 4; ++m)
    #pragma unroll
    for (int r = 0; r < 4; ++r) kmax[m][r] = 0u;

  const int er = wn * 16 + crl;                 // B row within 64-code tile
  const unsigned esw = (unsigned)((er & 7) << 4);
  float ci = c_init[er];                        // tile 0 cols
  int cur = 0;

  for (int tile = 0; tile < 16; ++tile) {
    // 2-phase: issue next tile's staging BEFORE compute (T3 minimum)
    if (tile < 15) {
      const unsigned char* src = embbf + (tile + 1) * 32768 + w * 1024 + lane * 16;
      unsigned char* dst = &e_lds[cur ^ 1][w * 1024];
      #pragma unroll
      for (int i = 0; i < 4; ++i) gload_lds16(src + i * 8192, dst + i * 8192);
    }
    const float ci_next = (tile < 15) ? c_init[(tile + 1) * 64 + er] : 0.f;

    f32x4 acc[4];
    #pragma unroll
    for (int m = 0; m < 4; ++m) { acc[m][0] = ci; acc[m][1] = ci; acc[m][2] = ci; acc[m][3] = ci; }

    #pragma unroll
    for (int kb = 0; kb < 8; ++kb) {
      const unsigned db = (unsigned)(kb * 64 + g * 16) ^ esw;
      const bf16x8 bfr = *reinterpret_cast<const bf16x8*>(&e_lds[cur][er * 512 + db]);
      #pragma unroll
      for (int m = 0; m < 4; ++m)
        acc[m] = __builtin_amdgcn_mfma_f32_16x16x32_bf16(afrag[m][kb], bfr, acc[m], 0, 0, 0);
    }

    // epilogue: 2 VALU ops per element (and_or + max)
    const unsigned colcode = (unsigned)(1023 - (tile * 64 + er));
    #pragma unroll
    for (int m = 0; m < 4; ++m)
      #pragma unroll
      for (int r = 0; r < 4; ++r) {
        FU fu; fu.f = acc[m][r];
        const unsigned key = (fu.u & 0xFFFFFC00u) | colcode;
        kmax[m][r] = kmax[m][r] > key ? kmax[m][r] : key;
      }

    ci = ci_next;
    __syncthreads();                            // drains vmcnt: next tile ready
    cur ^= 1;
  }

  // ---- reduce over the 16 col-lanes of each row-group
  #pragma unroll
  for (int s = 1; s <= 8; s <<= 1)
    #pragma unroll
    for (int m = 0; m < 4; ++m)
      #pragma unroll
      for (int r = 0; r < 4; ++r) {
        const unsigned o = __shfl_xor(kmax[m][r], s, 64);
        kmax[m][r] = kmax[m][r] > o ? kmax[m][r] : o;
      }

  // combine the 4 wn-waves' partial argmax per row
  unsigned* kbuf = reinterpret_cast<unsigned*>(e_lds[1]);   // 128 x 4 u32
  if (crl == 0) {
    #pragma unroll
    for (int m = 0; m < 4; ++m)
      #pragma unroll
      for (int r = 0; r < 4; ++r)
        kbuf[(wm * 64 + m * 16 + g * 4 + r) * 4 + wn] = kmax[m][r];
  }
  __syncthreads();
  if (t < 128) {
    const unsigned k0 = kbuf[t * 4 + 0], k1 = kbuf[t * 4 + 1];
    const unsigned k2 = kbuf[t * 4 + 2], k3 = kbuf[t * 4 + 3];
    unsigned km = k0 > k1 ? k0 : k1;
    const unsigned kn = k2 > k3 ? k2 : k3;
    km = km > kn ? km : kn;
    idx_out[row0 + t] = 1023 - (int)(km & 1023u);
  }
}

// ---------------- K3: gather + straight-through output + loss partials ------
// Thread = 4 consecutive hw x 4 consecutive d: all traffic float4/int4 (16B/lane).
__global__ __launch_bounds__(256) void k_out(const float* __restrict__ z,
                                             const float* __restrict__ emb,
                                             const int* __restrict__ idx,
                                             float* __restrict__ out,
                                             float* __restrict__ partials) {
  const int t = threadIdx.x;
  const int gid = blockIdx.x * 256 + t;         // 0..524287
  const int hw_q = gid & 255;                   // hw quad
  const int d_c  = (gid >> 8) & 63;             // d quad
  const int b    = gid >> 14;                   // 0..31
  const int n0   = b * 1024 + hw_q * 4;
  const int d0   = d_c * 4;
  const size_t base = (size_t)b * (D * HW) + (size_t)d0 * HW + hw_q * 4;

  const int4 k4 = *reinterpret_cast<const int4*>(idx + n0);
  const float4 e0 = *reinterpret_cast<const float4*>(emb + (size_t)k4.x * D + d0);
  const float4 e1 = *reinterpret_cast<const float4*>(emb + (size_t)k4.y * D + d0);
  const float4 e2 = *reinterpret_cast<const float4*>(emb + (size_t)k4.z * D + d0);
  const float4 e3 = *reinterpret_cast<const float4*>(emb + (size_t)k4.w * D + d0);
  const float* ep[4] = {reinterpret_cast<const float*>(&e0), reinterpret_cast<const float*>(&e1),
                        reinterpret_cast<const float*>(&e2), reinterpret_cast<const float*>(&e3)};

  float lsum = 0.f;
  #pragma unroll
  for (int q = 0; q < 4; ++q) {                 // q: d index (rows of out)
    const float4 zq = *reinterpret_cast<const float4*>(z + base + (size_t)q * HW);
    const float zz[4] = {zq.x, zq.y, zq.z, zq.w};
    float oo[4];
    #pragma unroll
    for (int j = 0; j < 4; ++j) {               // j: hw sub-index
      const float dl = ep[j][q] - zz[j];
      oo[j] = zz[j] + dl;                        // straight-through, same fp32 expr as ref
      lsum += dl * dl;
    }
    float4 ov; ov.x = oo[0]; ov.y = oo[1]; ov.z = oo[2]; ov.w = oo[3];
    *reinterpret_cast<float4*>(out + base + (size_t)q * HW) = ov;
  }

  #pragma unroll
  for (int m = 1; m < 64; m <<= 1) lsum += __shfl_xor(lsum, m, 64);
  __shared__ float wsum[4];
  if ((t & 63) == 0) wsum[t >> 6] = lsum;
  __syncthreads();
  if (t == 0) partials[blockIdx.x] = wsum[0] + wsum[1] + wsum[2] + wsum[3];
}

// ---------------- K4: final loss reduce -------------------------------------
__global__ __launch_bounds__(256) void k_loss(const float* __restrict__ partials,
                                              float* __restrict__ out_loss) {
  const int t = threadIdx.x;
  float s = 0.f;
  #pragma unroll
  for (int i = 0; i < 8; ++i) s += partials[t + i * 256];
  #pragma unroll
  for (int m = 1; m < 64; m <<= 1) s += __shfl_xor(s, m, 64);
  __shared__ float wsum[4];
  if ((t & 63) == 0) wsum[t >> 6] = s;
  __syncthreads();
  if (t == 0)
    out_loss[0] = 1.25f * (wsum[0] + wsum[1] + wsum[2] + wsum[3]) * (1.0f / 8388608.0f);
}

extern "C" void kernel_launch(void* const* d_in, const int* in_sizes, int n_in,
                              void* d_out, int out_size, void* d_ws, size_t ws_size,
                              hipStream_t stream) {
  (void)in_sizes; (void)n_in; (void)out_size; (void)ws_size;
  const float* z   = (const float*)d_in[0];
  const float* emb = (const float*)d_in[1];
  float* out = (float*)d_out;
  unsigned char* ws = (unsigned char*)d_ws;

  k_prep<<<256, 256, 0, stream>>>(emb, ws);
  k_dist<<<256, 512, 0, stream>>>(z, ws + WS_EMBBF,
                                  (const float*)(ws + WS_CINIT),
                                  (int*)(ws + WS_IDX));
  k_out<<<2048, 256, 0, stream>>>(z, emb, (const int*)(ws + WS_IDX), out,
                                  (float*)(ws + WS_PART));
  k_loss<<<1, 256, 0, stream>>>((const float*)(ws + WS_PART), out + TOTAL);
}

// Round 5
// 53.608 us; speedup vs baseline: 1.1379x; 1.0960x over previous
//
#include <hip/hip_runtime.h>
#include <hip/hip_bf16.h>
#include <stdint.h>

// Problem constants
#define D       256
#define KCB     1024
#define HW      1024        // 32*32
#define NROWS   32768       // 32*32*32
#define TOTAL   8388608     // 32*256*32*32
#define BM      128         // z-rows per WG in k_dist

// ws layout (bytes)
#define WS_EMBBF 0          // 1024*256*2 = 524288, pre-swizzled bf16, 16 tiles x 32KB
#define WS_CINIT 524288     // 1024*4  : 1 - 0.5*|e|^2 per code
#define WS_IDX   528384     // 32768*4
#define WS_PART  659456     // 256*4   : per-WG sum of (q-z)^2

typedef __bf16 bf16x8 __attribute__((ext_vector_type(8)));
typedef float  f32x4  __attribute__((ext_vector_type(4)));
typedef unsigned int u32x4 __attribute__((ext_vector_type(4)));
typedef unsigned int u32x2 __attribute__((ext_vector_type(2)));

union Pack8 { __bf16 h[8]; u32x4 u; };
union Pack4 { __bf16 h[4]; u32x2 u; };
union FU    { float f; unsigned u; };

__device__ __forceinline__ void gload_lds16(const void* g, void* l) {
  __builtin_amdgcn_global_load_lds(
      (__attribute__((address_space(1))) void*)(uintptr_t)g,
      (__attribute__((address_space(3))) void*)l, 16, 0, 0);
}

// ---------------- K1: c_init (1 - 0.5|e|^2) + bf16 emb, pre-swizzled --------
// One wave per codebook row. Data byte-col c stored at c ^ ((row&7)<<4).
__global__ __launch_bounds__(256) void k_prep(const float* __restrict__ emb,
                                              unsigned char* __restrict__ ws) {
  const int t = threadIdx.x;
  const int wave = (blockIdx.x * 256 + t) >> 6;  // 0..1023 = emb row
  const int lane = t & 63;
  const float4 v = *reinterpret_cast<const float4*>(emb + wave * D + lane * 4);
  float ss = v.x * v.x + v.y * v.y + v.z * v.z + v.w * v.w;
  #pragma unroll
  for (int m = 1; m < 64; m <<= 1) ss += __shfl_xor(ss, m, 64);
  if (lane == 0)
    *reinterpret_cast<float*>(ws + WS_CINIT + wave * 4) = 1.0f - 0.5f * ss;

  Pack4 p;
  p.h[0] = (__bf16)v.x; p.h[1] = (__bf16)v.y; p.h[2] = (__bf16)v.z; p.h[3] = (__bf16)v.w;
  const int tile = wave >> 6, rl = wave & 63;
  const unsigned u = (unsigned)(lane * 8) ^ (unsigned)((rl & 7) << 4);
  *reinterpret_cast<u32x2*>(ws + WS_EMBBF + tile * 32768 + rl * 512 + u) = p.u;
}

// ---------------- K2: fused distances + argmin + loss -----------------------
// 256 WGs x 512 threads (8 waves, 2/SIMD). WG = 128 z-rows vs all 1024 codes.
// acc = 1 + z.e - .5|e|^2 (positive -> IEEE bits monotone). argmin(dist) =
// argmax(acc) via packed key (bits&~1023)|(1023-col). Loss from the winner:
// sum_d (q-z)^2 = |z|^2 - 2*(acc_w - 1), |z|^2 taken in fp32 during staging.
__global__ __launch_bounds__(512, 2) void k_dist(const float* __restrict__ z,
                                                 const unsigned char* __restrict__ embbf,
                                                 const float* __restrict__ c_init,
                                                 int* __restrict__ idx_out,
                                                 float* __restrict__ partials) {
  __shared__ unsigned char z_lds[BM * 512];      // 64KB swizzled bf16 [row][256 d]
  __shared__ unsigned char e_lds[2][32768];      // 64KB dbuf; [1] doubles as scratch/kbuf
  __shared__ float zsq_buf[4][128];              // per-row |z|^2 partials (by kc group)
  __shared__ float wl[8];

  const int t    = threadIdx.x;
  const int lane = t & 63;
  const int w    = t >> 6;        // 0..7
  const int wm   = w >> 2;        // 0..1 : 64-row block
  const int wn   = w & 3;         // 0..3 : 16-col block within each 64-col tile
  const int crl  = lane & 15;
  const int g    = lane >> 4;     // 0..3
  const int row0 = blockIdx.x * BM;
  const int b    = row0 >> 10;
  const int hw0  = row0 & 1023;
  const float* zb = z + (size_t)b * (D * HW) + hw0;

  // Prefetch code tile 0 into e_lds[0] (async, overlaps z staging)
  #pragma unroll
  for (int i = 0; i < 4; ++i)
    gload_lds16(embbf + i * 8192 + w * 1024 + lane * 16,
                &e_lds[0][i * 8192 + w * 1024]);

  // ---- Stage z: float4 global -> f32 scratch (64d x 128hw) -> bf16 swz LDS
  float* scratch = reinterpret_cast<float*>(e_lds[1]);
  const int row = t & 127;
  float zsq_part = 0.f;
  for (int c = 0; c < 4; ++c) {
    #pragma unroll
    for (int i = 0; i < 4; ++i) {
      const int s   = t + i * 512;          // 0..2047
      const int dl  = s >> 5;               // 0..63
      const int hw4 = s & 31;               // 0..31
      *reinterpret_cast<float4*>(scratch + dl * 128 + hw4 * 4) =
          *reinterpret_cast<const float4*>(zb + (size_t)(c * 64 + dl) * HW + hw4 * 4);
    }
    __syncthreads();
    #pragma unroll
    for (int kk = 0; kk < 2; ++kk) {
      const int kc = (t >> 7) + kk * 4;     // 0..7 (8 d each)
      Pack8 p;
      #pragma unroll
      for (int q = 0; q < 8; ++q) {
        const float f = scratch[(kc * 8 + q) * 128 + row];
        zsq_part += f * f;
        p.h[q] = (__bf16)f;
      }
      const unsigned u = (unsigned)(c * 128 + kc * 16) ^ (unsigned)((row & 7) << 4);
      *reinterpret_cast<u32x4*>(&z_lds[row * 512 + u]) = p.u;
    }
    __syncthreads();
  }
  zsq_buf[t >> 7][row] = zsq_part;

  // ---- Hoist A-fragments: 64 rows x full K per wave (128 VGPR, stationary)
  bf16x8 afrag[4][8];
  #pragma unroll
  for (int m = 0; m < 4; ++m) {
    const int rl = wm * 64 + m * 16 + crl;
    const unsigned s = (unsigned)((rl & 7) << 4);
    #pragma unroll
    for (int kb = 0; kb < 8; ++kb) {
      const unsigned db = (unsigned)(kb * 64 + g * 16) ^ s;
      afrag[m][kb] = *reinterpret_cast<const bf16x8*>(&z_lds[rl * 512 + db]);
    }
  }
  __syncthreads();   // tile 0 staged & visible; scratch dead

  unsigned kmax[4][4];
  #pragma unroll
  for (int m = 0; m < 4; ++m)
    #pragma unroll
    for (int r = 0; r < 4; ++r) kmax[m][r] = 0u;

  const int er = wn * 16 + crl;                 // B row within 64-code tile
  const unsigned esw = (unsigned)((er & 7) << 4);
  float ci = c_init[er];                        // tile 0 cols
  int cur = 0;

  for (int tile = 0; tile < 16; ++tile) {
    // 2-phase: issue next tile's staging BEFORE compute (T3 minimum)
    if (tile < 15) {
      const unsigned char* src = embbf + (tile + 1) * 32768 + w * 1024 + lane * 16;
      unsigned char* dst = &e_lds[cur ^ 1][w * 1024];
      #pragma unroll
      for (int i = 0; i < 4; ++i) gload_lds16(src + i * 8192, dst + i * 8192);
    }
    const float ci_next = (tile < 15) ? c_init[(tile + 1) * 64 + er] : 0.f;

    f32x4 acc[4];
    #pragma unroll
    for (int m = 0; m < 4; ++m) { acc[m][0] = ci; acc[m][1] = ci; acc[m][2] = ci; acc[m][3] = ci; }

    #pragma unroll
    for (int kb = 0; kb < 8; ++kb) {
      const unsigned db = (unsigned)(kb * 64 + g * 16) ^ esw;
      const bf16x8 bfr = *reinterpret_cast<const bf16x8*>(&e_lds[cur][er * 512 + db]);
      #pragma unroll
      for (int m = 0; m < 4; ++m)
        acc[m] = __builtin_amdgcn_mfma_f32_16x16x32_bf16(afrag[m][kb], bfr, acc[m], 0, 0, 0);
    }

    // epilogue: 2 VALU ops per element (and_or + max)
    const unsigned colcode = (unsigned)(1023 - (tile * 64 + er));
    #pragma unroll
    for (int m = 0; m < 4; ++m)
      #pragma unroll
      for (int r = 0; r < 4; ++r) {
        FU fu; fu.f = acc[m][r];
        const unsigned key = (fu.u & 0xFFFFFC00u) | colcode;
        kmax[m][r] = kmax[m][r] > key ? kmax[m][r] : key;
      }

    ci = ci_next;
    __syncthreads();                            // drains vmcnt: next tile ready
    cur ^= 1;
  }

  // ---- reduce over the 16 col-lanes of each row-group
  #pragma unroll
  for (int s = 1; s <= 8; s <<= 1)
    #pragma unroll
    for (int m = 0; m < 4; ++m)
      #pragma unroll
      for (int r = 0; r < 4; ++r) {
        const unsigned o = __shfl_xor(kmax[m][r], s, 64);
        kmax[m][r] = kmax[m][r] > o ? kmax[m][r] : o;
      }

  // combine the 4 wn-waves' partial argmax per row
  unsigned* kbuf = reinterpret_cast<unsigned*>(e_lds[1]);   // 128 x 4 u32
  if (crl == 0) {
    #pragma unroll
    for (int m = 0; m < 4; ++m)
      #pragma unroll
      for (int r = 0; r < 4; ++r)
        kbuf[(wm * 64 + m * 16 + g * 4 + r) * 4 + wn] = kmax[m][r];
  }
  __syncthreads();

  float myloss = 0.f;
  if (t < 128) {
    const unsigned k0 = kbuf[t * 4 + 0], k1 = kbuf[t * 4 + 1];
    const unsigned k2 = kbuf[t * 4 + 2], k3 = kbuf[t * 4 + 3];
    unsigned km = k0 > k1 ? k0 : k1;
    const unsigned kn = k2 > k3 ? k2 : k3;
    km = km > kn ? km : kn;
    idx_out[row0 + t] = 1023 - (int)(km & 1023u);
    FU fu; fu.u = km & 0xFFFFFC00u;             // winner acc (trunc, +ve -> valid)
    const float zsq = zsq_buf[0][t] + zsq_buf[1][t] + zsq_buf[2][t] + zsq_buf[3][t];
    myloss = zsq - 2.0f * (fu.f - 1.0f);        // sum_d (q - z)^2 for this row
  }
  #pragma unroll
  for (int m = 1; m < 64; m <<= 1) myloss += __shfl_xor(myloss, m, 64);
  if ((t & 63) == 0) wl[t >> 6] = myloss;
  __syncthreads();
  if (t == 0) partials[blockIdx.x] = wl[0] + wl[1];   // only waves 0,1 nonzero
}

// ---------------- K3: pure gather + output write ----------------------------
// out = z + (q - z) == q to 1 ulp; write emb[idx] directly. No z traffic.
__global__ __launch_bounds__(256) void k_out(const float* __restrict__ emb,
                                             const int* __restrict__ idx,
                                             float* __restrict__ out) {
  const int t = threadIdx.x;
  const int gid = blockIdx.x * 256 + t;         // 0..524287
  const int hw_q = gid & 255;                   // hw quad
  const int d_c  = (gid >> 8) & 63;             // d quad
  const int b    = gid >> 14;                   // 0..31
  const int n0   = b * 1024 + hw_q * 4;
  const int d0   = d_c * 4;
  const size_t base = (size_t)b * (D * HW) + (size_t)d0 * HW + hw_q * 4;

  const int4 k4 = *reinterpret_cast<const int4*>(idx + n0);
  const float4 e0 = *reinterpret_cast<const float4*>(emb + (size_t)k4.x * D + d0);
  const float4 e1 = *reinterpret_cast<const float4*>(emb + (size_t)k4.y * D + d0);
  const float4 e2 = *reinterpret_cast<const float4*>(emb + (size_t)k4.z * D + d0);
  const float4 e3 = *reinterpret_cast<const float4*>(emb + (size_t)k4.w * D + d0);
  const float* ep[4] = {reinterpret_cast<const float*>(&e0), reinterpret_cast<const float*>(&e1),
                        reinterpret_cast<const float*>(&e2), reinterpret_cast<const float*>(&e3)};

  #pragma unroll
  for (int q = 0; q < 4; ++q) {                 // q: d index (rows of out)
    float4 ov;
    ov.x = ep[0][q]; ov.y = ep[1][q]; ov.z = ep[2][q]; ov.w = ep[3][q];
    *reinterpret_cast<float4*>(out + base + (size_t)q * HW) = ov;
  }
}

// ---------------- K4: final loss reduce -------------------------------------
__global__ __launch_bounds__(256) void k_loss(const float* __restrict__ partials,
                                              float* __restrict__ out_loss) {
  const int t = threadIdx.x;
  float s = partials[t];                        // 256 partials
  #pragma unroll
  for (int m = 1; m < 64; m <<= 1) s += __shfl_xor(s, m, 64);
  __shared__ float wsum[4];
  if ((t & 63) == 0) wsum[t >> 6] = s;
  __syncthreads();
  if (t == 0)
    out_loss[0] = 1.25f * (wsum[0] + wsum[1] + wsum[2] + wsum[3]) * (1.0f / 8388608.0f);
}

extern "C" void kernel_launch(void* const* d_in, const int* in_sizes, int n_in,
                              void* d_out, int out_size, void* d_ws, size_t ws_size,
                              hipStream_t stream) {
  (void)in_sizes; (void)n_in; (void)out_size; (void)ws_size;
  const float* z   = (const float*)d_in[0];
  const float* emb = (const float*)d_in[1];
  float* out = (float*)d_out;
  unsigned char* ws = (unsigned char*)d_ws;

  k_prep<<<256, 256, 0, stream>>>(emb, ws);
  k_dist<<<256, 512, 0, stream>>>(z, ws + WS_EMBBF,
                                  (const float*)(ws + WS_CINIT),
                                  (int*)(ws + WS_IDX),
                                  (float*)(ws + WS_PART));
  k_out<<<2048, 256, 0, stream>>>(emb, (const int*)(ws + WS_IDX), out);
  k_loss<<<1, 256, 0, stream>>>((const float*)(ws + WS_PART), out + TOTAL);
}

// Round 7
// 46.698 us; speedup vs baseline: 1.3063x; 1.1480x over previous
//
#include <hip/hip_runtime.h>
#include <hip/hip_bf16.h>
#include <stdint.h>

// Problem constants
#define D       256
#define KCB     1024
#define HW      1024        // 32*32
#define NROWS   32768       // 32*32*32
#define TOTAL   8388608     // 32*256*32*32
#define BM      128         // z-rows per WG in k_fused

// ws layout (bytes)
#define WS_EMBBF 0          // 1024*256*2 = 524288, pre-swizzled bf16, 16 tiles x 32KB
#define WS_CINIT 524288     // 1024*4  : 1 - 0.5*|e|^2 per code

typedef __bf16 bf16x8 __attribute__((ext_vector_type(8)));
typedef float  f32x4  __attribute__((ext_vector_type(4)));
typedef unsigned int u32x4 __attribute__((ext_vector_type(4)));
typedef unsigned int u32x2 __attribute__((ext_vector_type(2)));

union Pack8 { __bf16 h[8]; u32x4 u; };
union Pack4 { __bf16 h[4]; u32x2 u; };
union FU    { float f; unsigned u; };

__device__ __forceinline__ void gload_lds16(const void* g, void* l) {
  __builtin_amdgcn_global_load_lds(
      (__attribute__((address_space(1))) void*)(uintptr_t)g,
      (__attribute__((address_space(3))) void*)l, 16, 0, 0);
}

// ---------------- K1: c_init (1 - 0.5|e|^2) + bf16 emb, pre-swizzled --------
// One wave per codebook row. Data byte-col c stored at c ^ ((row&7)<<4).
// Also zeroes the loss accumulator slot (out[TOTAL]).
__global__ __launch_bounds__(256) void k_prep(const float* __restrict__ emb,
                                              unsigned char* __restrict__ ws,
                                              float* __restrict__ loss_slot) {
  const int t = threadIdx.x;
  if (blockIdx.x == 0 && t == 0) *loss_slot = 0.0f;
  const int wave = (blockIdx.x * 256 + t) >> 6;  // 0..1023 = emb row
  const int lane = t & 63;
  const float4 v = *reinterpret_cast<const float4*>(emb + wave * D + lane * 4);
  float ss = v.x * v.x + v.y * v.y + v.z * v.z + v.w * v.w;
  #pragma unroll
  for (int m = 1; m < 64; m <<= 1) ss += __shfl_xor(ss, m, 64);
  if (lane == 0)
    *reinterpret_cast<float*>(ws + WS_CINIT + wave * 4) = 1.0f - 0.5f * ss;

  Pack4 p;
  p.h[0] = (__bf16)v.x; p.h[1] = (__bf16)v.y; p.h[2] = (__bf16)v.z; p.h[3] = (__bf16)v.w;
  const int tile = wave >> 6, rl = wave & 63;
  const unsigned u = (unsigned)(lane * 8) ^ (unsigned)((rl & 7) << 4);
  *reinterpret_cast<u32x2*>(ws + WS_EMBBF + tile * 32768 + rl * 512 + u) = p.u;
}

// ---------------- K2: fused dist + argmin + loss + gather + output ----------
// 256 WGs x 512 threads (8 waves). WG = 128 z-rows (one b, 128 hw) vs 1024 codes.
// acc = 1 + z.e - .5|e|^2 (positive -> IEEE bits monotone). argmin(dist) =
// argmax(acc) via packed key (bits&~1023)|(1023-col). Loss from winner key:
// sum_d (q-z)^2 = |z|^2 - 2*(acc_w - 1). Then: coalesced gather of the 128
// winner emb rows into T2-swizzled LDS, transposed coalesced write of out.
__global__ __launch_bounds__(512, 2) void k_fused(const float* __restrict__ z,
                                                  const unsigned char* __restrict__ embbf,
                                                  const float* __restrict__ c_init,
                                                  const float* __restrict__ embf32,
                                                  float* __restrict__ out,
                                                  float* __restrict__ loss_slot) {
  __shared__ unsigned char smem[131072];   // [0,64K)=z_lds  [64K,96K)=ebuf0  [96K,128K)=ebuf1/scratch
  __shared__ float zsq_buf[4][128];        // per-row |z|^2 partials (by kc group)
  __shared__ int   idx_l[128];             // per-row winner index
  __shared__ float wl[2];

  unsigned char* z_lds = smem;             // named, no pointer arrays (addrspace bug)
  unsigned char* ebuf0 = smem + 65536;
  unsigned char* ebuf1 = smem + 98304;

  const int t    = threadIdx.x;
  const int lane = t & 63;
  const int w    = t >> 6;        // 0..7
  const int wm   = w >> 2;        // 0..1 : 64-row block
  const int wn   = w & 3;         // 0..3 : 16-col block within each 64-col tile
  const int crl  = lane & 15;
  const int g    = lane >> 4;     // 0..3
  const int row0 = blockIdx.x * BM;
  const int b    = row0 >> 10;
  const int hw0  = row0 & 1023;
  const float* zb = z + (size_t)b * (D * HW) + hw0;

  // Prefetch code tile 0 into ebuf0 (async, overlaps z staging)
  #pragma unroll
  for (int i = 0; i < 4; ++i)
    gload_lds16(embbf + i * 8192 + w * 1024 + lane * 16,
                ebuf0 + i * 8192 + w * 1024);

  // ---- Stage z: float4 global -> f32 scratch (64d x 128hw) -> bf16 swz LDS
  float* scratch = reinterpret_cast<float*>(ebuf1);
  const int row = t & 127;
  float zsq_part = 0.f;
  for (int c = 0; c < 4; ++c) {
    #pragma unroll
    for (int i = 0; i < 4; ++i) {
      const int s   = t + i * 512;          // 0..2047
      const int dl  = s >> 5;               // 0..63
      const int hw4 = s & 31;               // 0..31
      *reinterpret_cast<float4*>(scratch + dl * 128 + hw4 * 4) =
          *reinterpret_cast<const float4*>(zb + (size_t)(c * 64 + dl) * HW + hw4 * 4);
    }
    __syncthreads();
    #pragma unroll
    for (int kk = 0; kk < 2; ++kk) {
      const int kc = (t >> 7) + kk * 4;     // 0..7 (8 d each)
      Pack8 p;
      #pragma unroll
      for (int q = 0; q < 8; ++q) {
        const float f = scratch[(kc * 8 + q) * 128 + row];
        zsq_part += f * f;
        p.h[q] = (__bf16)f;
      }
      const unsigned u = (unsigned)(c * 128 + kc * 16) ^ (unsigned)((row & 7) << 4);
      *reinterpret_cast<u32x4*>(&z_lds[row * 512 + u]) = p.u;
    }
    __syncthreads();
  }
  zsq_buf[t >> 7][row] = zsq_part;

  // ---- Hoist A-fragments: 64 rows x full K per wave (128 VGPR, stationary)
  bf16x8 afrag[4][8];
  #pragma unroll
  for (int m = 0; m < 4; ++m) {
    const int rl = wm * 64 + m * 16 + crl;
    const unsigned s = (unsigned)((rl & 7) << 4);
    #pragma unroll
    for (int kb = 0; kb < 8; ++kb) {
      const unsigned db = (unsigned)(kb * 64 + g * 16) ^ s;
      afrag[m][kb] = *reinterpret_cast<const bf16x8*>(&z_lds[rl * 512 + db]);
    }
  }
  __syncthreads();   // tile 0 staged & visible; scratch dead

  unsigned kmax[4][4];
  #pragma unroll
  for (int m = 0; m < 4; ++m)
    #pragma unroll
    for (int r = 0; r < 4; ++r) kmax[m][r] = 0u;

  const int er = wn * 16 + crl;                 // B row within 64-code tile
  const unsigned esw = (unsigned)((er & 7) << 4);
  float ci = c_init[er];                        // tile 0 cols
  int cur = 0;

  for (int tile = 0; tile < 16; ++tile) {
    // 2-phase: issue next tile's staging BEFORE compute (T3 minimum)
    if (tile < 15) {
      const unsigned char* src = embbf + (tile + 1) * 32768 + w * 1024 + lane * 16;
      unsigned char* dst = smem + 65536 + ((cur ^ 1) << 15) + w * 1024;
      #pragma unroll
      for (int i = 0; i < 4; ++i) gload_lds16(src + i * 8192, dst + i * 8192);
    }
    const float ci_next = (tile < 15) ? c_init[(tile + 1) * 64 + er] : 0.f;

    f32x4 acc[4];
    #pragma unroll
    for (int m = 0; m < 4; ++m) { acc[m][0] = ci; acc[m][1] = ci; acc[m][2] = ci; acc[m][3] = ci; }

    const unsigned char* ecur = smem + 65536 + (cur << 15);
    #pragma unroll
    for (int kb = 0; kb < 8; ++kb) {
      const unsigned db = (unsigned)(kb * 64 + g * 16) ^ esw;
      const bf16x8 bfr = *reinterpret_cast<const bf16x8*>(&ecur[er * 512 + db]);
      #pragma unroll
      for (int m = 0; m < 4; ++m)
        acc[m] = __builtin_amdgcn_mfma_f32_16x16x32_bf16(afrag[m][kb], bfr, acc[m], 0, 0, 0);
    }

    // epilogue: 2 VALU ops per element (and_or + max)
    const unsigned colcode = (unsigned)(1023 - (tile * 64 + er));
    #pragma unroll
    for (int m = 0; m < 4; ++m)
      #pragma unroll
      for (int r = 0; r < 4; ++r) {
        FU fu; fu.f = acc[m][r];
        const unsigned key = (fu.u & 0xFFFFFC00u) | colcode;
        kmax[m][r] = kmax[m][r] > key ? kmax[m][r] : key;
      }

    ci = ci_next;
    __syncthreads();                            // drains vmcnt: next tile ready
    cur ^= 1;
  }

  // ---- reduce over the 16 col-lanes of each row-group
  #pragma unroll
  for (int s = 1; s <= 8; s <<= 1)
    #pragma unroll
    for (int m = 0; m < 4; ++m)
      #pragma unroll
      for (int r = 0; r < 4; ++r) {
        const unsigned o = __shfl_xor(kmax[m][r], s, 64);
        kmax[m][r] = kmax[m][r] > o ? kmax[m][r] : o;
      }

  // combine the 4 wn-waves' partial argmax per row (kbuf in ebuf0; loop done)
  unsigned* kbuf = reinterpret_cast<unsigned*>(ebuf0);   // 128 x 4 u32
  if (crl == 0) {
    #pragma unroll
    for (int m = 0; m < 4; ++m)
      #pragma unroll
      for (int r = 0; r < 4; ++r)
        kbuf[(wm * 64 + m * 16 + g * 4 + r) * 4 + wn] = kmax[m][r];
  }
  __syncthreads();

  float myloss = 0.f;
  if (t < 128) {
    const unsigned k0 = kbuf[t * 4 + 0], k1 = kbuf[t * 4 + 1];
    const unsigned k2 = kbuf[t * 4 + 2], k3 = kbuf[t * 4 + 3];
    unsigned km = k0 > k1 ? k0 : k1;
    const unsigned kn = k2 > k3 ? k2 : k3;
    km = km > kn ? km : kn;
    idx_l[t] = 1023 - (int)(km & 1023u);
    FU fu; fu.u = km & 0xFFFFFC00u;             // winner acc (trunc, +ve -> valid)
    const float zsq = zsq_buf[0][t] + zsq_buf[1][t] + zsq_buf[2][t] + zsq_buf[3][t];
    myloss = zsq - 2.0f * (fu.f - 1.0f);        // sum_d (q - z)^2 for this row
  }
  if (w < 2) {
    #pragma unroll
    for (int m = 1; m < 64; m <<= 1) myloss += __shfl_xor(myloss, m, 64);
    if (lane == 0) wl[w] = myloss;
  }
  __syncthreads();   // idx_l/wl visible; kbuf reads done -> smem reusable as gb

  if (t == 0)
    atomicAdd(loss_slot, (wl[0] + wl[1]) * (1.25f / 8388608.0f));

  // ---- Gather: 128 winner emb rows, coalesced (1KB/row), T2-swizzled LDS
  unsigned char* gb = smem;                     // 128 rows x 1KB = 128KB
  const float4* emb4 = reinterpret_cast<const float4*>(embf32);
  #pragma unroll
  for (int i = 0; i < 16; ++i) {
    const int r = w * 16 + i;
    const int k = idx_l[r];                     // LDS broadcast (uniform per wave)
    const float4 v = emb4[(size_t)k * 64 + lane];
    *reinterpret_cast<float4*>(
        &gb[r * 1024 + ((unsigned)(lane * 16) ^ (unsigned)((r & 7) << 4))]) = v;
  }
  __syncthreads();

  // ---- Transposed write-out: lane<->row (consecutive r -> swizzle spreads),
  // b128 LDS read (4 d) -> 4 coalesced scalar stores (256B/instr over hw).
  {
    const int rb  = (w & 1) * 64;
    const int dq0 = (w >> 1) * 16;
    const int r   = rb + lane;
    const unsigned rsw = (unsigned)((r & 7) << 4);
    float* outb = out + (size_t)b * (D * HW) + (size_t)(hw0 + r);
    #pragma unroll
    for (int i = 0; i < 16; ++i) {
      const int dq = dq0 + i;
      const f32x4 v = *reinterpret_cast<const f32x4*>(
          &gb[r * 1024 + ((unsigned)(dq * 16) ^ rsw)]);
      #pragma unroll
      for (int q = 0; q < 4; ++q)
        outb[(size_t)(dq * 4 + q) * HW] = v[q];
    }
  }
}

extern "C" void kernel_launch(void* const* d_in, const int* in_sizes, int n_in,
                              void* d_out, int out_size, void* d_ws, size_t ws_size,
                              hipStream_t stream) {
  (void)in_sizes; (void)n_in; (void)out_size; (void)ws_size;
  const float* z   = (const float*)d_in[0];
  const float* emb = (const float*)d_in[1];
  float* out = (float*)d_out;
  unsigned char* ws = (unsigned char*)d_ws;

  k_prep<<<256, 256, 0, stream>>>(emb, ws, out + TOTAL);
  k_fused<<<256, 512, 0, stream>>>(z, ws + WS_EMBBF,
                                   (const float*)(ws + WS_CINIT),
                                   emb, out, out + TOTAL);
}